// Round 10
// baseline (719.209 us; speedup 1.0000x reference)
//
#include <hip/hip_runtime.h>

#define N_NODES 100000
#define N_EDGES 1600000
#define IN_DIM 128
#define HID 256
#define N_CLS 32
#define BN_EPS 1e-5f

#define SCAN_CHUNK 1024
#define SCAN_NB ((N_NODES + SCAN_CHUNK - 1) / SCAN_CHUNK)   // 98
#define GEMM_NBY ((N_NODES + 127) / 128)                    // 782
#define GEMM_NB (GEMM_NBY * 2)                              // 1564 blocks (2 n-tiles)

typedef unsigned short bf16;
typedef __attribute__((ext_vector_type(8))) short short8;
typedef __attribute__((ext_vector_type(4))) float float4v;
typedef __attribute__((ext_vector_type(2))) float floatx2;

__device__ __forceinline__ float bf2f(bf16 h) {
    return __uint_as_float(((unsigned int)h) << 16);
}
__device__ __forceinline__ bf16 f2bf(float f) {
    unsigned int u = __float_as_uint(f);
    u += 0x7FFFu + ((u >> 16) & 1u);   // round-to-nearest-even
    return (bf16)(u >> 16);
}
__device__ __forceinline__ float blo(unsigned int u) { return __uint_as_float(u << 16); }
__device__ __forceinline__ float bhi(unsigned int u) { return __uint_as_float(u & 0xFFFF0000u); }
__device__ __forceinline__ unsigned int pack2(float lo, float hi) {
    return (unsigned int)f2bf(lo) | ((unsigned int)f2bf(hi) << 16);
}

// fp8 (OCP e4m3 on gfx950) hardware conversions
__device__ __forceinline__ void acc8_fp8(uint2 w, float* a) {
    floatx2 f0 = __builtin_amdgcn_cvt_pk_f32_fp8(w.x, false);
    floatx2 f1 = __builtin_amdgcn_cvt_pk_f32_fp8(w.x, true);
    floatx2 f2 = __builtin_amdgcn_cvt_pk_f32_fp8(w.y, false);
    floatx2 f3 = __builtin_amdgcn_cvt_pk_f32_fp8(w.y, true);
    a[0] += f0.x; a[1] += f0.y; a[2] += f1.x; a[3] += f1.y;
    a[4] += f2.x; a[5] += f2.y; a[6] += f3.x; a[7] += f3.y;
}
__device__ __forceinline__ unsigned int pack4_fp8(float a, float b, float c, float d) {
    int p = 0;
    p = __builtin_amdgcn_cvt_pk_fp8_f32(a, b, p, false);
    p = __builtin_amdgcn_cvt_pk_fp8_f32(c, d, p, true);
    return (unsigned int)p;
}

// ---------------- CSR build ----------------

__global__ void hist_kernel(const int* __restrict__ dst, int* __restrict__ counts, int n) {
    int i = blockIdx.x * blockDim.x + threadIdx.x;
    if (i < n) atomicAdd(&counts[dst[i]], 1);
}

__global__ void scan1_kernel(const int* __restrict__ counts, int* __restrict__ bsums) {
    __shared__ int wsum[4];
    int base = blockIdx.x * SCAN_CHUNK + threadIdx.x * 4;
    int s = 0;
    if (base + 4 <= N_NODES) {
        int4 v = *(const int4*)(counts + base);
        s = v.x + v.y + v.z + v.w;
    } else {
        for (int j = 0; j < 4; ++j) if (base + j < N_NODES) s += counts[base + j];
    }
    for (int d = 32; d > 0; d >>= 1) s += __shfl_down(s, d, 64);
    if ((threadIdx.x & 63) == 0) wsum[threadIdx.x >> 6] = s;
    __syncthreads();
    if (threadIdx.x == 0) bsums[blockIdx.x] = wsum[0] + wsum[1] + wsum[2] + wsum[3];
}

__global__ void scan2_kernel(const int* __restrict__ bsums, int* __restrict__ boffs) {
    __shared__ int sh[128];
    int i = threadIdx.x;
    int v = (i < SCAN_NB) ? bsums[i] : 0;
    sh[i] = v;
    __syncthreads();
    for (int d = 1; d < 128; d <<= 1) {
        int t = (i >= d) ? sh[i - d] : 0;
        __syncthreads();
        sh[i] += t;
        __syncthreads();
    }
    if (i < SCAN_NB) boffs[i] = sh[i] - v;
}

__global__ void scan3_kernel(const int* __restrict__ counts, const int* __restrict__ boffs,
                             int* __restrict__ off) {
    __shared__ int sh[256];
    int tid = threadIdx.x;
    int base = blockIdx.x * SCAN_CHUNK + tid * 4;
    int c0 = 0, c1 = 0, c2 = 0, c3 = 0;
    if (base + 4 <= N_NODES) {
        int4 v = *(const int4*)(counts + base);
        c0 = v.x; c1 = v.y; c2 = v.z; c3 = v.w;
    } else {
        if (base + 0 < N_NODES) c0 = counts[base + 0];
        if (base + 1 < N_NODES) c1 = counts[base + 1];
        if (base + 2 < N_NODES) c2 = counts[base + 2];
        if (base + 3 < N_NODES) c3 = counts[base + 3];
    }
    int ts = c0 + c1 + c2 + c3;
    sh[tid] = ts;
    __syncthreads();
    for (int d = 1; d < 256; d <<= 1) {
        int t = (tid >= d) ? sh[tid - d] : 0;
        __syncthreads();
        sh[tid] += t;
        __syncthreads();
    }
    int run = boffs[blockIdx.x] + sh[tid] - ts;
    if (base + 0 < N_NODES) off[base + 0] = run; run += c0;
    if (base + 1 < N_NODES) off[base + 1] = run; run += c1;
    if (base + 2 < N_NODES) off[base + 2] = run; run += c2;
    if (base + 3 < N_NODES) off[base + 3] = run;
    if (blockIdx.x == 0 && tid == 0) off[N_NODES] = N_EDGES;
}

__global__ void fill_kernel(const int* __restrict__ src, const int* __restrict__ dst,
                            const int* __restrict__ off, int* __restrict__ cursor,
                            int* __restrict__ csr, int n) {
    int i = blockIdx.x * blockDim.x + threadIdx.x;
    if (i < n) {
        int d = dst[i];
        int p = atomicAdd(&cursor[d], 1);
        csr[off[d] + p] = src[i];
    }
}

// ---------------- x fp32 -> bf16 + fp8 ----------------

__global__ void convert_x_kernel(const float* __restrict__ x, bf16* __restrict__ xb,
                                 unsigned char* __restrict__ xf8) {
    int i = blockIdx.x * blockDim.x + threadIdx.x;
    int total4 = N_NODES * IN_DIM / 4;
    if (i >= total4) return;
    float4 v = ((const float4*)x)[i];
    ushort4 r;
    r.x = f2bf(v.x); r.y = f2bf(v.y); r.z = f2bf(v.z); r.w = f2bf(v.w);
    ((ushort4*)xb)[i] = r;
    ((unsigned int*)xf8)[i] = pack4_fp8(v.x, v.y, v.z, v.w);
}

// ---------------- combined weight prep ----------------

__global__ void prep_weights_kernel(const float* __restrict__ W1l, const float* __restrict__ W1r,
                                    const float* __restrict__ W2l, const float* __restrict__ W2r,
                                    const float* __restrict__ Wfc,
                                    bf16* __restrict__ w1lt, bf16* __restrict__ w1rt,
                                    bf16* __restrict__ w2lt, bf16* __restrict__ w2rt,
                                    bf16* __restrict__ wfct) {
    const int S1 = IN_DIM * HID;   // 32768
    const int S2 = HID * HID;      // 65536
    const int S3 = HID * N_CLS;    // 8192
    int i = blockIdx.x * blockDim.x + threadIdx.x;
    if (i < 2 * S1 + 2 * S2) {
        const float* W; bf16* Wt; int K, idx;
        if (i < S1)          { W = W1l; Wt = w1lt; K = IN_DIM; idx = i; }
        else if (i < 2 * S1) { W = W1r; Wt = w1rt; K = IN_DIM; idx = i - S1; }
        else if (i < 2 * S1 + S2) { W = W2l; Wt = w2lt; K = HID; idx = i - 2 * S1; }
        else                 { W = W2r; Wt = w2rt; K = HID; idx = i - 2 * S1 - S2; }
        int k = idx / HID, n = idx - k * HID;
        Wt[(size_t)n * K + k] = f2bf(W[idx]);
    } else if (i < 2 * S1 + 2 * S2 + S3) {
        int idx = i - 2 * S1 - 2 * S2;       // idx = k*32 + n
        int k = idx >> 5, n = idx & 31;
        wfct[(size_t)n * HID + k] = f2bf(Wfc[idx]);
    }
}

// ---------------- mean aggregation (fp8 gathers, sub-wave per node, x4 unroll) ----------------

__global__ void aggregate1_kernel(const unsigned char* __restrict__ xf8, const int* __restrict__ off,
                                  const int* __restrict__ csr, bf16* __restrict__ out) {
    int t = blockIdx.x * blockDim.x + threadIdx.x;
    int node = t >> 4;
    int sl = t & 15;
    if (node >= N_NODES) return;
    int s = off[node], e = off[node + 1];
    float inv = 1.0f / (float)max(e - s, 1);
    const uint2* f = (const uint2*)xf8;   // row = 16 uint2
    float a[8] = {0.f, 0.f, 0.f, 0.f, 0.f, 0.f, 0.f, 0.f};
    int i = s;
    for (; i + 4 <= e; i += 4) {
        int u0 = csr[i], u1 = csr[i + 1], u2 = csr[i + 2], u3 = csr[i + 3];
        uint2 w0 = f[(size_t)u0 * 16 + sl];
        uint2 w1 = f[(size_t)u1 * 16 + sl];
        uint2 w2 = f[(size_t)u2 * 16 + sl];
        uint2 w3 = f[(size_t)u3 * 16 + sl];
        acc8_fp8(w0, a); acc8_fp8(w1, a); acc8_fp8(w2, a); acc8_fp8(w3, a);
    }
    for (; i < e; ++i) {
        uint2 w = f[(size_t)csr[i] * 16 + sl];
        acc8_fp8(w, a);
    }
    uint4 r;
    r.x = pack2(a[0] * inv, a[1] * inv);
    r.y = pack2(a[2] * inv, a[3] * inv);
    r.z = pack2(a[4] * inv, a[5] * inv);
    r.w = pack2(a[6] * inv, a[7] * inv);
    ((uint4*)out)[(size_t)node * 16 + sl] = r;
}

__global__ void aggregate2_kernel(const unsigned char* __restrict__ hf8, const int* __restrict__ off,
                                  const int* __restrict__ csr, bf16* __restrict__ out) {
    int t = blockIdx.x * blockDim.x + threadIdx.x;
    int node = t >> 5;
    int sl = t & 31;
    if (node >= N_NODES) return;
    int s = off[node], e = off[node + 1];
    float inv = 1.0f / (float)max(e - s, 1);
    const uint2* f = (const uint2*)hf8;   // row = 32 uint2
    float a[8] = {0.f, 0.f, 0.f, 0.f, 0.f, 0.f, 0.f, 0.f};
    int i = s;
    for (; i + 4 <= e; i += 4) {
        int u0 = csr[i], u1 = csr[i + 1], u2 = csr[i + 2], u3 = csr[i + 3];
        uint2 w0 = f[(size_t)u0 * 32 + sl];
        uint2 w1 = f[(size_t)u1 * 32 + sl];
        uint2 w2 = f[(size_t)u2 * 32 + sl];
        uint2 w3 = f[(size_t)u3 * 32 + sl];
        acc8_fp8(w0, a); acc8_fp8(w1, a); acc8_fp8(w2, a); acc8_fp8(w3, a);
    }
    for (; i < e; ++i) {
        uint2 w = f[(size_t)csr[i] * 32 + sl];
        acc8_fp8(w, a);
    }
    uint4 r;
    r.x = pack2(a[0] * inv, a[1] * inv);
    r.y = pack2(a[2] * inv, a[3] * inv);
    r.z = pack2(a[4] * inv, a[5] * inv);
    r.w = pack2(a[6] * inv, a[7] * inv);
    ((uint4*)out)[(size_t)node * 32 + sl] = r;
}

// ---------------- MFMA dual GEMM, register-prefetch pipeline, fused BN-stats ----------------

#define LSTRIDE 36  // 32 + 4 pad (bf16): row stride 18 dwords -> 16 distinct bank starts

template <typename T>
__device__ __forceinline__ void gemm_pass_mfma(
    const T* __restrict__ Ap, const bf16* __restrict__ Wp, int K,
    int tile_m, int tile_n, int M, int tid,
    bf16* As, bf16* Ws, float4v (*acc)[4]) {
    const int lane = tid & 63;
    const int wave = tid >> 6;
    const int rw = (wave >> 1) * 64;
    const int cw = (wave & 1) * 64;
    const int lrow = lane & 15;
    const int quad = lane >> 4;
    // staging: 512 16B-chunks (128 rows x 4 segs) per matrix; thread handles chunks tid, tid+256
    const int row0 = tid >> 2, seg = tid & 3;
    const int row1 = row0 + 64;

    uint4 va0, va1, vw0, vw1;
    {   // preload k0 = 0
        int gr0 = tile_m + row0, gr1 = tile_m + row1;
        va0 = (uint4){0u, 0u, 0u, 0u}; va1 = (uint4){0u, 0u, 0u, 0u};
        if (gr0 < M) va0 = *(const uint4*)(Ap + (size_t)gr0 * K + seg * 8);
        if (gr1 < M) va1 = *(const uint4*)(Ap + (size_t)gr1 * K + seg * 8);
        vw0 = *(const uint4*)(Wp + (size_t)(tile_n + row0) * K + seg * 8);
        vw1 = *(const uint4*)(Wp + (size_t)(tile_n + row1) * K + seg * 8);
    }

    for (int k0 = 0; k0 < K; k0 += 32) {
        __syncthreads();   // prior iteration's ds_reads complete before overwrite
        *(uint4*)(As + row0 * LSTRIDE + seg * 8) = va0;
        *(uint4*)(As + row1 * LSTRIDE + seg * 8) = va1;
        *(uint4*)(Ws + row0 * LSTRIDE + seg * 8) = vw0;
        *(uint4*)(Ws + row1 * LSTRIDE + seg * 8) = vw1;
        __syncthreads();
        // prefetch next K-tile while MFMAs run (vmcnt wait lands at next store)
        if (k0 + 32 < K) {
            int kn = k0 + 32;
            int gr0 = tile_m + row0, gr1 = tile_m + row1;
            uint4 z = {0u, 0u, 0u, 0u};
            va0 = z; va1 = z;
            if (gr0 < M) va0 = *(const uint4*)(Ap + (size_t)gr0 * K + kn + seg * 8);
            if (gr1 < M) va1 = *(const uint4*)(Ap + (size_t)gr1 * K + kn + seg * 8);
            vw0 = *(const uint4*)(Wp + (size_t)(tile_n + row0) * K + kn + seg * 8);
            vw1 = *(const uint4*)(Wp + (size_t)(tile_n + row1) * K + kn + seg * 8);
        }
        short8 a[4], b[4];
#pragma unroll
        for (int i = 0; i < 4; ++i)
            a[i] = *(const short8*)(As + (rw + i * 16 + lrow) * LSTRIDE + quad * 8);
#pragma unroll
        for (int j = 0; j < 4; ++j)
            b[j] = *(const short8*)(Ws + (cw + j * 16 + lrow) * LSTRIDE + quad * 8);
#pragma unroll
        for (int i = 0; i < 4; ++i)
#pragma unroll
            for (int j = 0; j < 4; ++j)
                acc[i][j] = __builtin_amdgcn_mfma_f32_16x16x32_bf16(a[i], b[j], acc[i][j], 0, 0, 0);
    }
    __syncthreads();
}

template <typename TB>
__global__ __launch_bounds__(256) void gemm_dual_mfma(
    const bf16* __restrict__ A, const bf16* __restrict__ WtA, int KA,
    const TB* __restrict__ B, const bf16* __restrict__ WtB, int KB,
    const float* __restrict__ bias, bf16* __restrict__ C, int M,
    float* __restrict__ psum, float* __restrict__ psq) {
    __shared__ bf16 As[128 * LSTRIDE];
    __shared__ bf16 Ws[128 * LSTRIDE];
    __shared__ float sred[4][64];
    __shared__ float qred[4][64];
    const int tid = threadIdx.x;
    const int lane = tid & 63;
    const int wave = tid >> 6;
    const int rw = (wave >> 1) * 64;
    const int cw = (wave & 1) * 64;
    const int lrow = lane & 15;
    const int quad = lane >> 4;
    const int tile_m = blockIdx.y * 128;
    const int tile_n = blockIdx.x * 128;

    float4v acc[4][4];
#pragma unroll
    for (int i = 0; i < 4; ++i)
#pragma unroll
        for (int j = 0; j < 4; ++j) acc[i][j] = (float4v){0.f, 0.f, 0.f, 0.f};

    gemm_pass_mfma(A, WtA, KA, tile_m, tile_n, M, tid, As, Ws, acc);
    gemm_pass_mfma(B, WtB, KB, tile_m, tile_n, M, tid, As, Ws, acc);
    // (gemm_pass ends with __syncthreads: all ds_reads done, As reusable)

    // ---- epilogue: C/D layout col=lane&15, row=quad*4+reg [verified m89] ----
    // Per-wave LDS slice (16x64 bf16 = 2 KB) -> coalesced 16B global stores.
    bf16* slice = As + wave * 1024;
    float bvj[4];
#pragma unroll
    for (int j = 0; j < 4; ++j) bvj[j] = bias[tile_n + cw + j * 16 + lrow];
    float cs[4] = {0.f, 0.f, 0.f, 0.f}, cq[4] = {0.f, 0.f, 0.f, 0.f};

#pragma unroll
    for (int i = 0; i < 4; ++i) {
#pragma unroll
        for (int j = 0; j < 4; ++j) {
#pragma unroll
            for (int r = 0; r < 4; ++r) {
                int row = tile_m + rw + i * 16 + quad * 4 + r;
                float v = acc[i][j][r] + bvj[j];
                if (row < M) { cs[j] += v; cq[j] += v * v; }
                slice[(quad * 4 + r) * 64 + j * 16 + lrow] = f2bf(v);
            }
        }
        __syncthreads();
        // readback: 128 uint4 chunks (16 rows x 8 chunks), lane handles 2
#pragma unroll
        for (int c = 0; c < 2; ++c) {
            int ch = lane + c * 64;
            int lr = ch >> 3, sg = ch & 7;
            int grow = tile_m + rw + i * 16 + lr;
            if (grow < M) {
                uint4 v = *(const uint4*)(slice + lr * 64 + sg * 8);
                *(uint4*)(C + (size_t)grow * HID + tile_n + cw + sg * 8) = v;
            }
        }
        __syncthreads();
    }

    // reduce across the 4 quads that share each (j,lrow) column
#pragma unroll
    for (int j = 0; j < 4; ++j) {
        cs[j] += __shfl_xor(cs[j], 16, 64); cs[j] += __shfl_xor(cs[j], 32, 64);
        cq[j] += __shfl_xor(cq[j], 16, 64); cq[j] += __shfl_xor(cq[j], 32, 64);
    }
    if (quad == 0) {
#pragma unroll
        for (int j = 0; j < 4; ++j) {
            sred[wave][j * 16 + lrow] = cs[j];
            qred[wave][j * 16 + lrow] = cq[j];
        }
    }
    __syncthreads();
    int bid = blockIdx.y * gridDim.x + blockIdx.x;
    if (tid < 128) {
        int grp = tid >> 6, idx = tid & 63;
        psum[(size_t)bid * 128 + tid] = sred[grp][idx] + sred[grp + 2][idx];
    } else {
        int t = tid - 128;
        int grp = t >> 6, idx = t & 63;
        psq[(size_t)bid * 128 + t] = qred[grp][idx] + qred[grp + 2][idx];
    }
}

// reduce per-block partials -> stats[0..255]=sum, stats[256..511]=sumsq
__global__ void bn_finalize_kernel(const float* __restrict__ psum, const float* __restrict__ psq,
                                   float* __restrict__ stats, int nby) {
    const float* src = blockIdx.y ? psq : psum;
    int c = threadIdx.x;           // 0..255 = global column
    int bx = c >> 7, cl = c & 127;
    int per = (nby + gridDim.x - 1) / gridDim.x;
    int b0 = blockIdx.x * per, b1 = min(b0 + per, nby);
    float s = 0.f;
    for (int by = b0; by < b1; ++by) s += src[(size_t)(by * 2 + bx) * 128 + cl];
    atomicAdd(&stats[blockIdx.y * HID + c], s);
}

// ---------------- BN apply + ReLU (layer 1; also emits fp8 copy for gather) ----------------

__global__ void bn_apply_relu_kernel(bf16* __restrict__ h, unsigned char* __restrict__ hf8,
                                     const float* __restrict__ stats,
                                     const float* __restrict__ g, const float* __restrict__ be,
                                     int M) {
    int i4 = blockIdx.x * blockDim.x + threadIdx.x;
    int total4 = M * (HID / 4);
    if (i4 >= total4) return;
    int col4 = i4 & (HID / 4 - 1);
    ushort4 v = ((const ushort4*)h)[i4];
    float invN = 1.0f / (float)M;
    float o[4] = {bf2f(v.x), bf2f(v.y), bf2f(v.z), bf2f(v.w)};
#pragma unroll
    for (int j = 0; j < 4; ++j) {
        int col = col4 * 4 + j;
        float mu = stats[col] * invN;
        float var = stats[HID + col] * invN - mu * mu;
        float sc = rsqrtf(var + BN_EPS) * g[col];
        float val = (o[j] - mu) * sc + be[col];
        o[j] = val > 0.f ? val : 0.f;
    }
    ushort4 r;
    r.x = f2bf(o[0]); r.y = f2bf(o[1]); r.z = f2bf(o[2]); r.w = f2bf(o[3]);
    ((ushort4*)h)[i4] = r;
    ((unsigned int*)hf8)[i4] = pack4_fp8(o[0], o[1], o[2], o[3]);
}

// ---------------- final FC (MFMA) with fused BN2+ReLU ----------------

#define BSTR 264   // 256 + 8 pad

__global__ __launch_bounds__(256) void fc_bn_mfma_kernel(
    const bf16* __restrict__ h, const float* __restrict__ stats,
    const float* __restrict__ g, const float* __restrict__ be,
    const bf16* __restrict__ WfcT, const float* __restrict__ bfc,
    float* __restrict__ out, int M) {
    __shared__ bf16 Bs[32 * BSTR];
    __shared__ float sc_s[HID], sh_s[HID];
    int tid = threadIdx.x;
    for (int i = tid; i < 32 * 32; i += 256) {   // 1024 16B chunks
        int rrow = i >> 5, seg = i & 31;
        *(uint4*)(Bs + rrow * BSTR + seg * 8) = *(const uint4*)(WfcT + (size_t)rrow * HID + seg * 8);
    }
    {
        float invN = 1.0f / (float)M;
        float mu = stats[tid] * invN;
        float var = stats[HID + tid] * invN - mu * mu;
        float s = rsqrtf(var + BN_EPS) * g[tid];
        sc_s[tid] = s;
        sh_s[tid] = be[tid] - mu * s;
    }
    __syncthreads();
    int wave = tid >> 6, lane = tid & 63, lrow = lane & 15, quad = lane >> 4;
    int row = blockIdx.x * 64 + wave * 16 + lrow;
    const bf16* hrow = h + (size_t)row * HID;
    float4v acc0 = {0.f, 0.f, 0.f, 0.f}, acc1 = {0.f, 0.f, 0.f, 0.f};
#pragma unroll
    for (int ks = 0; ks < 8; ++ks) {
        int k0 = ks * 32 + quad * 8;
        uint4 av = {0u, 0u, 0u, 0u};
        if (row < M) av = *(const uint4*)(hrow + k0);
        union { unsigned int u[4]; short8 s8; } cvt;
        unsigned int* avp = (unsigned int*)&av;
#pragma unroll
        for (int t = 0; t < 4; ++t) {
            int k = k0 + t * 2;
            float v0 = blo(avp[t]) * sc_s[k] + sh_s[k];
            float v1 = bhi(avp[t]) * sc_s[k + 1] + sh_s[k + 1];
            v0 = v0 > 0.f ? v0 : 0.f;
            v1 = v1 > 0.f ? v1 : 0.f;
            cvt.u[t] = pack2(v0, v1);
        }
        short8 b0 = *(const short8*)(Bs + lrow * BSTR + k0);
        short8 b1 = *(const short8*)(Bs + (16 + lrow) * BSTR + k0);
        acc0 = __builtin_amdgcn_mfma_f32_16x16x32_bf16(cvt.s8, b0, acc0, 0, 0, 0);
        acc1 = __builtin_amdgcn_mfma_f32_16x16x32_bf16(cvt.s8, b1, acc1, 0, 0, 0);
    }
    int orow = blockIdx.x * 64 + wave * 16 + quad * 4;
    float bv0 = bfc[lrow], bv1 = bfc[16 + lrow];
#pragma unroll
    for (int r = 0; r < 4; ++r) {
        int rr = orow + r;
        if (rr < M) {
            out[(size_t)rr * N_CLS + lrow] = acc0[r] + bv0;
            out[(size_t)rr * N_CLS + 16 + lrow] = acc1[r] + bv1;
        }
    }
}

// ---------------- launch ----------------

extern "C" void kernel_launch(void* const* d_in, const int* in_sizes, int n_in,
                              void* d_out, int out_size, void* d_ws, size_t ws_size,
                              hipStream_t stream) {
    const float* x   = (const float*)d_in[0];
    const int* esrc  = (const int*)d_in[1];
    const int* edst  = (const int*)d_in[2];
    const float* W1l = (const float*)d_in[3];
    const float* b1  = (const float*)d_in[4];
    const float* W1r = (const float*)d_in[5];
    const float* g1  = (const float*)d_in[6];
    const float* be1 = (const float*)d_in[7];
    const float* W2l = (const float*)d_in[8];
    const float* b2  = (const float*)d_in[9];
    const float* W2r = (const float*)d_in[10];
    const float* g2  = (const float*)d_in[11];
    const float* be2 = (const float*)d_in[12];
    const float* Wfc = (const float*)d_in[13];
    const float* bfc = (const float*)d_in[14];
    float* out = (float*)d_out;

    char* ws = (char*)d_ws;
    size_t o = 0;
    auto carve = [&](size_t bytes) {
        char* p = ws + o;
        o = (o + bytes + 255) & ~(size_t)255;
        return p;
    };
    int*   off    = (int*)carve((N_NODES + 1) * sizeof(int));
    int*   cursor = (int*)carve(N_NODES * sizeof(int));
    int*   csr    = (int*)carve(N_EDGES * sizeof(int));
    int*   bsums  = (int*)carve(SCAN_NB * sizeof(int));
    int*   boffs  = (int*)carve(SCAN_NB * sizeof(int));
    float* stats1 = (float*)carve(2 * HID * sizeof(float));
    float* stats2 = (float*)carve(2 * HID * sizeof(float));
    float* psum   = (float*)carve((size_t)GEMM_NB * 128 * sizeof(float));
    float* psq    = (float*)carve((size_t)GEMM_NB * 128 * sizeof(float));
    bf16*  w1lt   = (bf16*)carve((size_t)IN_DIM * HID * sizeof(bf16));
    bf16*  w1rt   = (bf16*)carve((size_t)IN_DIM * HID * sizeof(bf16));
    bf16*  w2lt   = (bf16*)carve((size_t)HID * HID * sizeof(bf16));
    bf16*  w2rt   = (bf16*)carve((size_t)HID * HID * sizeof(bf16));
    bf16*  wfct   = (bf16*)carve((size_t)N_CLS * HID * sizeof(bf16));
    bf16*  agg    = (bf16*)carve((size_t)N_NODES * HID * sizeof(bf16));
    bf16*  h1     = (bf16*)carve((size_t)N_NODES * HID * sizeof(bf16));
    bf16*  h2     = (bf16*)carve((size_t)N_NODES * HID * sizeof(bf16));
    // overlays inside the h2 region (lifetimes stream-ordered disjoint):
    //   xb  = h2[0   : 25.6MB]  bf16 x   — dead after gemm1
    //   xf8 = h2[25.6: 38.4MB]  fp8 x    — dead after aggregate1
    //   h1f8= h2[0   : 25.6MB]  fp8 bn(h1) — written post-gemm1, read by aggregate2,
    //                                        then gemm2 overwrites h2
    bf16*          xb   = h2;
    unsigned char* xf8  = (unsigned char*)h2 + (size_t)N_NODES * IN_DIM * sizeof(bf16);
    unsigned char* h1f8 = (unsigned char*)h2;

    if (o > ws_size) return;  // clean fail instead of fault

    hipMemsetAsync(cursor, 0, N_NODES * sizeof(int), stream);
    hipMemsetAsync(stats1, 0, 2 * HID * sizeof(float), stream);
    hipMemsetAsync(stats2, 0, 2 * HID * sizeof(float), stream);

    const int eb = (N_EDGES + 255) / 256;

    // CSR build (parallel scan)
    hist_kernel<<<eb, 256, 0, stream>>>(edst, cursor, N_EDGES);
    scan1_kernel<<<SCAN_NB, 256, 0, stream>>>(cursor, bsums);
    scan2_kernel<<<1, 128, 0, stream>>>(bsums, boffs);
    scan3_kernel<<<SCAN_NB, 256, 0, stream>>>(cursor, boffs, off);
    hipMemsetAsync(cursor, 0, N_NODES * sizeof(int), stream);
    fill_kernel<<<eb, 256, 0, stream>>>(esrc, edst, off, cursor, csr, N_EDGES);

    // prep: x -> bf16 + fp8, all weights -> bf16 transposed
    convert_x_kernel<<<(N_NODES * IN_DIM / 4 + 255) / 256, 256, 0, stream>>>(x, xb, xf8);
    {
        int total = 2 * IN_DIM * HID + 2 * HID * HID + HID * N_CLS;
        prep_weights_kernel<<<(total + 255) / 256, 256, 0, stream>>>(
            W1l, W1r, W2l, W2r, Wfc, w1lt, w1rt, w2lt, w2rt, wfct);
    }

    const dim3 ggrid(HID / 128, GEMM_NBY);

    // ---- layer 1 ----
    aggregate1_kernel<<<(N_NODES * 16 + 255) / 256, 256, 0, stream>>>(xf8, off, csr, agg);
    gemm_dual_mfma<bf16><<<ggrid, 256, 0, stream>>>(
        agg, w1lt, IN_DIM, xb, w1rt, IN_DIM, b1, h1, N_NODES, psum, psq);
    bn_finalize_kernel<<<dim3(8, 2), 256, 0, stream>>>(psum, psq, stats1, GEMM_NBY);
    {
        int total4 = N_NODES * (HID / 4);
        bn_apply_relu_kernel<<<(total4 + 255) / 256, 256, 0, stream>>>(h1, h1f8, stats1, g1, be1, N_NODES);
    }

    // ---- layer 2 ----
    aggregate2_kernel<<<(N_NODES * 32 + 255) / 256, 256, 0, stream>>>(h1f8, off, csr, agg);
    gemm_dual_mfma<bf16><<<ggrid, 256, 0, stream>>>(
        agg, w2lt, HID, h1, w2rt, HID, b2, h2, N_NODES, psum, psq);
    bn_finalize_kernel<<<dim3(8, 2), 256, 0, stream>>>(psum, psq, stats2, GEMM_NBY);

    // ---- final FC (MFMA) with fused BN2+ReLU ----
    fc_bn_mfma_kernel<<<(N_NODES + 63) / 64, 256, 0, stream>>>(
        h2, stats2, g2, be2, wfct, bfc, out, N_NODES);
}

// Round 11
// 576.803 us; speedup vs baseline: 1.2469x; 1.2469x over previous
//
#include <hip/hip_runtime.h>

#define N_NODES 100000
#define N_EDGES 1600000
#define IN_DIM 128
#define HID 256
#define N_CLS 32
#define BN_EPS 1e-5f

#define SCAN_CHUNK 1024
#define SCAN_NB ((N_NODES + SCAN_CHUNK - 1) / SCAN_CHUNK)   // 98
#define GEMM_NBY ((N_NODES + 127) / 128)                    // 782
#define GEMM_NB (GEMM_NBY * 2)                              // 1564 blocks (2 n-tiles)

typedef unsigned short bf16;
typedef __attribute__((ext_vector_type(8))) short short8;
typedef __attribute__((ext_vector_type(4))) float float4v;
typedef __attribute__((ext_vector_type(2))) float floatx2;

__device__ __forceinline__ float bf2f(bf16 h) {
    return __uint_as_float(((unsigned int)h) << 16);
}
__device__ __forceinline__ bf16 f2bf(float f) {
    unsigned int u = __float_as_uint(f);
    u += 0x7FFFu + ((u >> 16) & 1u);   // round-to-nearest-even
    return (bf16)(u >> 16);
}
__device__ __forceinline__ float blo(unsigned int u) { return __uint_as_float(u << 16); }
__device__ __forceinline__ float bhi(unsigned int u) { return __uint_as_float(u & 0xFFFF0000u); }
__device__ __forceinline__ unsigned int pack2(float lo, float hi) {
    return (unsigned int)f2bf(lo) | ((unsigned int)f2bf(hi) << 16);
}

// fp8 (OCP e4m3 on gfx950) hardware conversions
__device__ __forceinline__ void acc8_fp8(uint2 w, float* a) {
    floatx2 f0 = __builtin_amdgcn_cvt_pk_f32_fp8(w.x, false);
    floatx2 f1 = __builtin_amdgcn_cvt_pk_f32_fp8(w.x, true);
    floatx2 f2 = __builtin_amdgcn_cvt_pk_f32_fp8(w.y, false);
    floatx2 f3 = __builtin_amdgcn_cvt_pk_f32_fp8(w.y, true);
    a[0] += f0.x; a[1] += f0.y; a[2] += f1.x; a[3] += f1.y;
    a[4] += f2.x; a[5] += f2.y; a[6] += f3.x; a[7] += f3.y;
}
__device__ __forceinline__ unsigned int pack4_fp8(float a, float b, float c, float d) {
    int p = 0;
    p = __builtin_amdgcn_cvt_pk_fp8_f32(a, b, p, false);
    p = __builtin_amdgcn_cvt_pk_fp8_f32(c, d, p, true);
    return (unsigned int)p;
}

// ---------------- CSR build ----------------

__global__ void hist_kernel(const int* __restrict__ dst, int* __restrict__ counts, int n) {
    int i = blockIdx.x * blockDim.x + threadIdx.x;
    if (i < n) atomicAdd(&counts[dst[i]], 1);
}

__global__ void scan1_kernel(const int* __restrict__ counts, int* __restrict__ bsums) {
    __shared__ int wsum[4];
    int base = blockIdx.x * SCAN_CHUNK + threadIdx.x * 4;
    int s = 0;
    if (base + 4 <= N_NODES) {
        int4 v = *(const int4*)(counts + base);
        s = v.x + v.y + v.z + v.w;
    } else {
        for (int j = 0; j < 4; ++j) if (base + j < N_NODES) s += counts[base + j];
    }
    for (int d = 32; d > 0; d >>= 1) s += __shfl_down(s, d, 64);
    if ((threadIdx.x & 63) == 0) wsum[threadIdx.x >> 6] = s;
    __syncthreads();
    if (threadIdx.x == 0) bsums[blockIdx.x] = wsum[0] + wsum[1] + wsum[2] + wsum[3];
}

__global__ void scan2_kernel(const int* __restrict__ bsums, int* __restrict__ boffs) {
    __shared__ int sh[128];
    int i = threadIdx.x;
    int v = (i < SCAN_NB) ? bsums[i] : 0;
    sh[i] = v;
    __syncthreads();
    for (int d = 1; d < 128; d <<= 1) {
        int t = (i >= d) ? sh[i - d] : 0;
        __syncthreads();
        sh[i] += t;
        __syncthreads();
    }
    if (i < SCAN_NB) boffs[i] = sh[i] - v;
}

__global__ void scan3_kernel(const int* __restrict__ counts, const int* __restrict__ boffs,
                             int* __restrict__ off) {
    __shared__ int sh[256];
    int tid = threadIdx.x;
    int base = blockIdx.x * SCAN_CHUNK + tid * 4;
    int c0 = 0, c1 = 0, c2 = 0, c3 = 0;
    if (base + 4 <= N_NODES) {
        int4 v = *(const int4*)(counts + base);
        c0 = v.x; c1 = v.y; c2 = v.z; c3 = v.w;
    } else {
        if (base + 0 < N_NODES) c0 = counts[base + 0];
        if (base + 1 < N_NODES) c1 = counts[base + 1];
        if (base + 2 < N_NODES) c2 = counts[base + 2];
        if (base + 3 < N_NODES) c3 = counts[base + 3];
    }
    int ts = c0 + c1 + c2 + c3;
    sh[tid] = ts;
    __syncthreads();
    for (int d = 1; d < 256; d <<= 1) {
        int t = (tid >= d) ? sh[tid - d] : 0;
        __syncthreads();
        sh[tid] += t;
        __syncthreads();
    }
    int run = boffs[blockIdx.x] + sh[tid] - ts;
    if (base + 0 < N_NODES) off[base + 0] = run; run += c0;
    if (base + 1 < N_NODES) off[base + 1] = run; run += c1;
    if (base + 2 < N_NODES) off[base + 2] = run; run += c2;
    if (base + 3 < N_NODES) off[base + 3] = run;
    if (blockIdx.x == 0 && tid == 0) off[N_NODES] = N_EDGES;
}

__global__ void fill_kernel(const int* __restrict__ src, const int* __restrict__ dst,
                            const int* __restrict__ off, int* __restrict__ cursor,
                            int* __restrict__ csr, int n) {
    int i = blockIdx.x * blockDim.x + threadIdx.x;
    if (i < n) {
        int d = dst[i];
        int p = atomicAdd(&cursor[d], 1);
        csr[off[d] + p] = src[i];
    }
}

// ---------------- x fp32 -> bf16 + fp8 ----------------

__global__ void convert_x_kernel(const float* __restrict__ x, bf16* __restrict__ xb,
                                 unsigned char* __restrict__ xf8) {
    int i = blockIdx.x * blockDim.x + threadIdx.x;
    int total4 = N_NODES * IN_DIM / 4;
    if (i >= total4) return;
    float4 v = ((const float4*)x)[i];
    ushort4 r;
    r.x = f2bf(v.x); r.y = f2bf(v.y); r.z = f2bf(v.z); r.w = f2bf(v.w);
    ((ushort4*)xb)[i] = r;
    ((unsigned int*)xf8)[i] = pack4_fp8(v.x, v.y, v.z, v.w);
}

// ---------------- combined weight prep ----------------

__global__ void prep_weights_kernel(const float* __restrict__ W1l, const float* __restrict__ W1r,
                                    const float* __restrict__ W2l, const float* __restrict__ W2r,
                                    const float* __restrict__ Wfc,
                                    bf16* __restrict__ w1lt, bf16* __restrict__ w1rt,
                                    bf16* __restrict__ w2lt, bf16* __restrict__ w2rt,
                                    bf16* __restrict__ wfct) {
    const int S1 = IN_DIM * HID;   // 32768
    const int S2 = HID * HID;      // 65536
    const int S3 = HID * N_CLS;    // 8192
    int i = blockIdx.x * blockDim.x + threadIdx.x;
    if (i < 2 * S1 + 2 * S2) {
        const float* W; bf16* Wt; int K, idx;
        if (i < S1)          { W = W1l; Wt = w1lt; K = IN_DIM; idx = i; }
        else if (i < 2 * S1) { W = W1r; Wt = w1rt; K = IN_DIM; idx = i - S1; }
        else if (i < 2 * S1 + S2) { W = W2l; Wt = w2lt; K = HID; idx = i - 2 * S1; }
        else                 { W = W2r; Wt = w2rt; K = HID; idx = i - 2 * S1 - S2; }
        int k = idx / HID, n = idx - k * HID;
        Wt[(size_t)n * K + k] = f2bf(W[idx]);
    } else if (i < 2 * S1 + 2 * S2 + S3) {
        int idx = i - 2 * S1 - 2 * S2;       // idx = k*32 + n
        int k = idx >> 5, n = idx & 31;
        wfct[(size_t)n * HID + k] = f2bf(Wfc[idx]);
    }
}

// ---------------- mean aggregation (fp8 gathers, sub-wave per node, x4 unroll) ----------------

__global__ void aggregate1_kernel(const unsigned char* __restrict__ xf8, const int* __restrict__ off,
                                  const int* __restrict__ csr, bf16* __restrict__ out) {
    int t = blockIdx.x * blockDim.x + threadIdx.x;
    int node = t >> 4;
    int sl = t & 15;
    if (node >= N_NODES) return;
    int s = off[node], e = off[node + 1];
    float inv = 1.0f / (float)max(e - s, 1);
    const uint2* f = (const uint2*)xf8;   // row = 16 uint2
    float a[8] = {0.f, 0.f, 0.f, 0.f, 0.f, 0.f, 0.f, 0.f};
    int i = s;
    for (; i + 4 <= e; i += 4) {
        int u0 = csr[i], u1 = csr[i + 1], u2 = csr[i + 2], u3 = csr[i + 3];
        uint2 w0 = f[(size_t)u0 * 16 + sl];
        uint2 w1 = f[(size_t)u1 * 16 + sl];
        uint2 w2 = f[(size_t)u2 * 16 + sl];
        uint2 w3 = f[(size_t)u3 * 16 + sl];
        acc8_fp8(w0, a); acc8_fp8(w1, a); acc8_fp8(w2, a); acc8_fp8(w3, a);
    }
    for (; i < e; ++i) {
        uint2 w = f[(size_t)csr[i] * 16 + sl];
        acc8_fp8(w, a);
    }
    uint4 r;
    r.x = pack2(a[0] * inv, a[1] * inv);
    r.y = pack2(a[2] * inv, a[3] * inv);
    r.z = pack2(a[4] * inv, a[5] * inv);
    r.w = pack2(a[6] * inv, a[7] * inv);
    ((uint4*)out)[(size_t)node * 16 + sl] = r;
}

__global__ void aggregate2_kernel(const unsigned char* __restrict__ hf8, const int* __restrict__ off,
                                  const int* __restrict__ csr, bf16* __restrict__ out) {
    int t = blockIdx.x * blockDim.x + threadIdx.x;
    int node = t >> 5;
    int sl = t & 31;
    if (node >= N_NODES) return;
    int s = off[node], e = off[node + 1];
    float inv = 1.0f / (float)max(e - s, 1);
    const uint2* f = (const uint2*)hf8;   // row = 32 uint2
    float a[8] = {0.f, 0.f, 0.f, 0.f, 0.f, 0.f, 0.f, 0.f};
    int i = s;
    for (; i + 4 <= e; i += 4) {
        int u0 = csr[i], u1 = csr[i + 1], u2 = csr[i + 2], u3 = csr[i + 3];
        uint2 w0 = f[(size_t)u0 * 32 + sl];
        uint2 w1 = f[(size_t)u1 * 32 + sl];
        uint2 w2 = f[(size_t)u2 * 32 + sl];
        uint2 w3 = f[(size_t)u3 * 32 + sl];
        acc8_fp8(w0, a); acc8_fp8(w1, a); acc8_fp8(w2, a); acc8_fp8(w3, a);
    }
    for (; i < e; ++i) {
        uint2 w = f[(size_t)csr[i] * 32 + sl];
        acc8_fp8(w, a);
    }
    uint4 r;
    r.x = pack2(a[0] * inv, a[1] * inv);
    r.y = pack2(a[2] * inv, a[3] * inv);
    r.z = pack2(a[4] * inv, a[5] * inv);
    r.w = pack2(a[6] * inv, a[7] * inv);
    ((uint4*)out)[(size_t)node * 32 + sl] = r;
}

// ---------------- MFMA dual GEMM (r9 K-loop, compiler-scheduled) + LDS write-combine epilogue ----------------

#define LSTRIDE 40  // 32 + 8 pad (bf16): 80 B rows, 16B-aligned everywhere

template <typename T>
__device__ __forceinline__ void gemm_pass_mfma(
    const T* __restrict__ Ap, const bf16* __restrict__ Wp, int K,
    int tile_m, int tile_n, int M, int tid,
    bf16* As, bf16* Ws, float4v (*acc)[4]) {
    const int lane = tid & 63;
    const int wave = tid >> 6;
    const int rw = (wave >> 1) * 64;
    const int cw = (wave & 1) * 64;
    const int lrow = lane & 15;
    const int quad = lane >> 4;

    for (int k0 = 0; k0 < K; k0 += 32) {
#pragma unroll
        for (int c = tid; c < 512; c += 256) {
            int row = c >> 2, seg = c & 3;
            int grow = tile_m + row;
            uint4 va = {0u, 0u, 0u, 0u};
            if (grow < M) va = *(const uint4*)(Ap + (size_t)grow * K + k0 + seg * 8);
            *(uint4*)(As + row * LSTRIDE + seg * 8) = va;
            uint4 vw = *(const uint4*)(Wp + (size_t)(tile_n + row) * K + k0 + seg * 8);
            *(uint4*)(Ws + row * LSTRIDE + seg * 8) = vw;
        }
        __syncthreads();
        short8 a[4], b[4];
#pragma unroll
        for (int i = 0; i < 4; ++i)
            a[i] = *(const short8*)(As + (rw + i * 16 + lrow) * LSTRIDE + quad * 8);
#pragma unroll
        for (int j = 0; j < 4; ++j)
            b[j] = *(const short8*)(Ws + (cw + j * 16 + lrow) * LSTRIDE + quad * 8);
#pragma unroll
        for (int i = 0; i < 4; ++i)
#pragma unroll
            for (int j = 0; j < 4; ++j)
                acc[i][j] = __builtin_amdgcn_mfma_f32_16x16x32_bf16(a[i], b[j], acc[i][j], 0, 0, 0);
        __syncthreads();
    }
}

template <typename TB>
__global__ __launch_bounds__(256) void gemm_dual_mfma(
    const bf16* __restrict__ A, const bf16* __restrict__ WtA, int KA,
    const TB* __restrict__ B, const bf16* __restrict__ WtB, int KB,
    const float* __restrict__ bias, bf16* __restrict__ C, int M,
    float* __restrict__ psum, float* __restrict__ psq) {
    __shared__ bf16 As[128 * LSTRIDE];
    __shared__ bf16 Ws[128 * LSTRIDE];
    __shared__ float sred[4][64];
    __shared__ float qred[4][64];
    const int tid = threadIdx.x;
    const int lane = tid & 63;
    const int wave = tid >> 6;
    const int rw = (wave >> 1) * 64;
    const int cw = (wave & 1) * 64;
    const int lrow = lane & 15;
    const int quad = lane >> 4;
    const int tile_m = blockIdx.y * 128;
    const int tile_n = blockIdx.x * 128;

    float4v acc[4][4];
#pragma unroll
    for (int i = 0; i < 4; ++i)
#pragma unroll
        for (int j = 0; j < 4; ++j) acc[i][j] = (float4v){0.f, 0.f, 0.f, 0.f};

    gemm_pass_mfma(A, WtA, KA, tile_m, tile_n, M, tid, As, Ws, acc);
    gemm_pass_mfma(B, WtB, KB, tile_m, tile_n, M, tid, As, Ws, acc);
    // (K-loop ends with __syncthreads: ds_reads done, As reusable)

    // ---- epilogue: C/D layout col=lane&15, row=quad*4+reg [verified m89] ----
    // Per-wave LDS slice (16x64 bf16 = 2 KB) -> coalesced 16B global stores.
    bf16* slice = As + wave * 1024;
    float bvj[4];
#pragma unroll
    for (int j = 0; j < 4; ++j) bvj[j] = bias[tile_n + cw + j * 16 + lrow];
    float cs[4] = {0.f, 0.f, 0.f, 0.f}, cq[4] = {0.f, 0.f, 0.f, 0.f};

#pragma unroll
    for (int i = 0; i < 4; ++i) {
#pragma unroll
        for (int j = 0; j < 4; ++j) {
#pragma unroll
            for (int r = 0; r < 4; ++r) {
                int row = tile_m + rw + i * 16 + quad * 4 + r;
                float v = acc[i][j][r] + bvj[j];
                if (row < M) { cs[j] += v; cq[j] += v * v; }
                slice[(quad * 4 + r) * 64 + j * 16 + lrow] = f2bf(v);
            }
        }
        __syncthreads();
        // readback: 128 uint4 chunks (16 rows x 8 chunks), lane handles 2
#pragma unroll
        for (int c = 0; c < 2; ++c) {
            int ch = lane + c * 64;
            int lr = ch >> 3, sg = ch & 7;
            int grow = tile_m + rw + i * 16 + lr;
            if (grow < M) {
                uint4 v = *(const uint4*)(slice + lr * 64 + sg * 8);
                *(uint4*)(C + (size_t)grow * HID + tile_n + cw + sg * 8) = v;
            }
        }
        __syncthreads();
    }

    // reduce across the 4 quads that share each (j,lrow) column
#pragma unroll
    for (int j = 0; j < 4; ++j) {
        cs[j] += __shfl_xor(cs[j], 16, 64); cs[j] += __shfl_xor(cs[j], 32, 64);
        cq[j] += __shfl_xor(cq[j], 16, 64); cq[j] += __shfl_xor(cq[j], 32, 64);
    }
    if (quad == 0) {
#pragma unroll
        for (int j = 0; j < 4; ++j) {
            sred[wave][j * 16 + lrow] = cs[j];
            qred[wave][j * 16 + lrow] = cq[j];
        }
    }
    __syncthreads();
    int bid = blockIdx.y * gridDim.x + blockIdx.x;
    if (tid < 128) {
        int grp = tid >> 6, idx = tid & 63;
        psum[(size_t)bid * 128 + tid] = sred[grp][idx] + sred[grp + 2][idx];
    } else {
        int t = tid - 128;
        int grp = t >> 6, idx = t & 63;
        psq[(size_t)bid * 128 + t] = qred[grp][idx] + qred[grp + 2][idx];
    }
}

// reduce per-block partials -> stats[0..255]=sum, stats[256..511]=sumsq
__global__ void bn_finalize_kernel(const float* __restrict__ psum, const float* __restrict__ psq,
                                   float* __restrict__ stats, int nby) {
    const float* src = blockIdx.y ? psq : psum;
    int c = threadIdx.x;           // 0..255 = global column
    int bx = c >> 7, cl = c & 127;
    int per = (nby + gridDim.x - 1) / gridDim.x;
    int b0 = blockIdx.x * per, b1 = min(b0 + per, nby);
    float s = 0.f;
    for (int by = b0; by < b1; ++by) s += src[(size_t)(by * 2 + bx) * 128 + cl];
    atomicAdd(&stats[blockIdx.y * HID + c], s);
}

// ---------------- BN apply + ReLU (layer 1; also emits fp8 copy for gather) ----------------

__global__ void bn_apply_relu_kernel(bf16* __restrict__ h, unsigned char* __restrict__ hf8,
                                     const float* __restrict__ stats,
                                     const float* __restrict__ g, const float* __restrict__ be,
                                     int M) {
    int i4 = blockIdx.x * blockDim.x + threadIdx.x;
    int total4 = M * (HID / 4);
    if (i4 >= total4) return;
    int col4 = i4 & (HID / 4 - 1);
    ushort4 v = ((const ushort4*)h)[i4];
    float invN = 1.0f / (float)M;
    float o[4] = {bf2f(v.x), bf2f(v.y), bf2f(v.z), bf2f(v.w)};
#pragma unroll
    for (int j = 0; j < 4; ++j) {
        int col = col4 * 4 + j;
        float mu = stats[col] * invN;
        float var = stats[HID + col] * invN - mu * mu;
        float sc = rsqrtf(var + BN_EPS) * g[col];
        float val = (o[j] - mu) * sc + be[col];
        o[j] = val > 0.f ? val : 0.f;
    }
    ushort4 r;
    r.x = f2bf(o[0]); r.y = f2bf(o[1]); r.z = f2bf(o[2]); r.w = f2bf(o[3]);
    ((ushort4*)h)[i4] = r;
    ((unsigned int*)hf8)[i4] = pack4_fp8(o[0], o[1], o[2], o[3]);
}

// ---------------- final FC (MFMA) with fused BN2+ReLU ----------------

#define BSTR 264   // 256 + 8 pad

__global__ __launch_bounds__(256) void fc_bn_mfma_kernel(
    const bf16* __restrict__ h, const float* __restrict__ stats,
    const float* __restrict__ g, const float* __restrict__ be,
    const bf16* __restrict__ WfcT, const float* __restrict__ bfc,
    float* __restrict__ out, int M) {
    __shared__ bf16 Bs[32 * BSTR];
    __shared__ float sc_s[HID], sh_s[HID];
    int tid = threadIdx.x;
    for (int i = tid; i < 32 * 32; i += 256) {   // 1024 16B chunks
        int rrow = i >> 5, seg = i & 31;
        *(uint4*)(Bs + rrow * BSTR + seg * 8) = *(const uint4*)(WfcT + (size_t)rrow * HID + seg * 8);
    }
    {
        float invN = 1.0f / (float)M;
        float mu = stats[tid] * invN;
        float var = stats[HID + tid] * invN - mu * mu;
        float s = rsqrtf(var + BN_EPS) * g[tid];
        sc_s[tid] = s;
        sh_s[tid] = be[tid] - mu * s;
    }
    __syncthreads();
    int wave = tid >> 6, lane = tid & 63, lrow = lane & 15, quad = lane >> 4;
    int row = blockIdx.x * 64 + wave * 16 + lrow;
    const bf16* hrow = h + (size_t)row * HID;
    float4v acc0 = {0.f, 0.f, 0.f, 0.f}, acc1 = {0.f, 0.f, 0.f, 0.f};
#pragma unroll
    for (int ks = 0; ks < 8; ++ks) {
        int k0 = ks * 32 + quad * 8;
        uint4 av = {0u, 0u, 0u, 0u};
        if (row < M) av = *(const uint4*)(hrow + k0);
        union { unsigned int u[4]; short8 s8; } cvt;
        unsigned int* avp = (unsigned int*)&av;
#pragma unroll
        for (int t = 0; t < 4; ++t) {
            int k = k0 + t * 2;
            float v0 = blo(avp[t]) * sc_s[k] + sh_s[k];
            float v1 = bhi(avp[t]) * sc_s[k + 1] + sh_s[k + 1];
            v0 = v0 > 0.f ? v0 : 0.f;
            v1 = v1 > 0.f ? v1 : 0.f;
            cvt.u[t] = pack2(v0, v1);
        }
        short8 b0 = *(const short8*)(Bs + lrow * BSTR + k0);
        short8 b1 = *(const short8*)(Bs + (16 + lrow) * BSTR + k0);
        acc0 = __builtin_amdgcn_mfma_f32_16x16x32_bf16(cvt.s8, b0, acc0, 0, 0, 0);
        acc1 = __builtin_amdgcn_mfma_f32_16x16x32_bf16(cvt.s8, b1, acc1, 0, 0, 0);
    }
    int orow = blockIdx.x * 64 + wave * 16 + quad * 4;
    float bv0 = bfc[lrow], bv1 = bfc[16 + lrow];
#pragma unroll
    for (int r = 0; r < 4; ++r) {
        int rr = orow + r;
        if (rr < M) {
            out[(size_t)rr * N_CLS + lrow] = acc0[r] + bv0;
            out[(size_t)rr * N_CLS + 16 + lrow] = acc1[r] + bv1;
        }
    }
}

// ---------------- launch ----------------

extern "C" void kernel_launch(void* const* d_in, const int* in_sizes, int n_in,
                              void* d_out, int out_size, void* d_ws, size_t ws_size,
                              hipStream_t stream) {
    const float* x   = (const float*)d_in[0];
    const int* esrc  = (const int*)d_in[1];
    const int* edst  = (const int*)d_in[2];
    const float* W1l = (const float*)d_in[3];
    const float* b1  = (const float*)d_in[4];
    const float* W1r = (const float*)d_in[5];
    const float* g1  = (const float*)d_in[6];
    const float* be1 = (const float*)d_in[7];
    const float* W2l = (const float*)d_in[8];
    const float* b2  = (const float*)d_in[9];
    const float* W2r = (const float*)d_in[10];
    const float* g2  = (const float*)d_in[11];
    const float* be2 = (const float*)d_in[12];
    const float* Wfc = (const float*)d_in[13];
    const float* bfc = (const float*)d_in[14];
    float* out = (float*)d_out;

    char* ws = (char*)d_ws;
    size_t o = 0;
    auto carve = [&](size_t bytes) {
        char* p = ws + o;
        o = (o + bytes + 255) & ~(size_t)255;
        return p;
    };
    int*   off    = (int*)carve((N_NODES + 1) * sizeof(int));
    int*   cursor = (int*)carve(N_NODES * sizeof(int));
    int*   csr    = (int*)carve(N_EDGES * sizeof(int));
    int*   bsums  = (int*)carve(SCAN_NB * sizeof(int));
    int*   boffs  = (int*)carve(SCAN_NB * sizeof(int));
    float* stats1 = (float*)carve(2 * HID * sizeof(float));
    float* stats2 = (float*)carve(2 * HID * sizeof(float));
    float* psum   = (float*)carve((size_t)GEMM_NB * 128 * sizeof(float));
    float* psq    = (float*)carve((size_t)GEMM_NB * 128 * sizeof(float));
    bf16*  w1lt   = (bf16*)carve((size_t)IN_DIM * HID * sizeof(bf16));
    bf16*  w1rt   = (bf16*)carve((size_t)IN_DIM * HID * sizeof(bf16));
    bf16*  w2lt   = (bf16*)carve((size_t)HID * HID * sizeof(bf16));
    bf16*  w2rt   = (bf16*)carve((size_t)HID * HID * sizeof(bf16));
    bf16*  wfct   = (bf16*)carve((size_t)N_CLS * HID * sizeof(bf16));
    bf16*  agg    = (bf16*)carve((size_t)N_NODES * HID * sizeof(bf16));
    bf16*  h1     = (bf16*)carve((size_t)N_NODES * HID * sizeof(bf16));
    bf16*  h2     = (bf16*)carve((size_t)N_NODES * HID * sizeof(bf16));
    // overlays inside the h2 region (lifetimes stream-ordered disjoint):
    //   xb  = h2[0   : 25.6MB]  bf16 x   — dead after gemm1
    //   xf8 = h2[25.6: 38.4MB]  fp8 x    — dead after aggregate1
    //   h1f8= h2[0   : 25.6MB]  fp8 bn(h1) — written post-gemm1, read by aggregate2,
    //                                        then gemm2 overwrites h2
    bf16*          xb   = h2;
    unsigned char* xf8  = (unsigned char*)h2 + (size_t)N_NODES * IN_DIM * sizeof(bf16);
    unsigned char* h1f8 = (unsigned char*)h2;

    if (o > ws_size) return;  // clean fail instead of fault

    hipMemsetAsync(cursor, 0, N_NODES * sizeof(int), stream);
    hipMemsetAsync(stats1, 0, 2 * HID * sizeof(float), stream);
    hipMemsetAsync(stats2, 0, 2 * HID * sizeof(float), stream);

    const int eb = (N_EDGES + 255) / 256;

    // CSR build (parallel scan)
    hist_kernel<<<eb, 256, 0, stream>>>(edst, cursor, N_EDGES);
    scan1_kernel<<<SCAN_NB, 256, 0, stream>>>(cursor, bsums);
    scan2_kernel<<<1, 128, 0, stream>>>(bsums, boffs);
    scan3_kernel<<<SCAN_NB, 256, 0, stream>>>(cursor, boffs, off);
    hipMemsetAsync(cursor, 0, N_NODES * sizeof(int), stream);
    fill_kernel<<<eb, 256, 0, stream>>>(esrc, edst, off, cursor, csr, N_EDGES);

    // prep: x -> bf16 + fp8, all weights -> bf16 transposed
    convert_x_kernel<<<(N_NODES * IN_DIM / 4 + 255) / 256, 256, 0, stream>>>(x, xb, xf8);
    {
        int total = 2 * IN_DIM * HID + 2 * HID * HID + HID * N_CLS;
        prep_weights_kernel<<<(total + 255) / 256, 256, 0, stream>>>(
            W1l, W1r, W2l, W2r, Wfc, w1lt, w1rt, w2lt, w2rt, wfct);
    }

    const dim3 ggrid(HID / 128, GEMM_NBY);

    // ---- layer 1 ----
    aggregate1_kernel<<<(N_NODES * 16 + 255) / 256, 256, 0, stream>>>(xf8, off, csr, agg);
    gemm_dual_mfma<bf16><<<ggrid, 256, 0, stream>>>(
        agg, w1lt, IN_DIM, xb, w1rt, IN_DIM, b1, h1, N_NODES, psum, psq);
    bn_finalize_kernel<<<dim3(8, 2), 256, 0, stream>>>(psum, psq, stats1, GEMM_NBY);
    {
        int total4 = N_NODES * (HID / 4);
        bn_apply_relu_kernel<<<(total4 + 255) / 256, 256, 0, stream>>>(h1, h1f8, stats1, g1, be1, N_NODES);
    }

    // ---- layer 2 ----
    aggregate2_kernel<<<(N_NODES * 32 + 255) / 256, 256, 0, stream>>>(h1f8, off, csr, agg);
    gemm_dual_mfma<bf16><<<ggrid, 256, 0, stream>>>(
        agg, w2lt, HID, h1, w2rt, HID, b2, h2, N_NODES, psum, psq);
    bn_finalize_kernel<<<dim3(8, 2), 256, 0, stream>>>(psum, psq, stats2, GEMM_NBY);

    // ---- final FC (MFMA) with fused BN2+ReLU ----
    fc_bn_mfma_kernel<<<(N_NODES + 63) / 64, 256, 0, stream>>>(
        h2, stats2, g2, be2, wfct, bfc, out, N_NODES);
}